// Round 9
// baseline (370.113 us; speedup 1.0000x reference)
//
#include <hip/hip_runtime.h>

#define BATCH  4
#define T_SEQ  2048
#define NH     16
#define DMODEL 1024
#define HD     64

typedef float    f32x4 __attribute__((ext_vector_type(4)));
typedef _Float16 f16x8 __attribute__((ext_vector_type(8)));
typedef _Float16 f16x4 __attribute__((ext_vector_type(4)));
typedef __fp16   h16x2 __attribute__((ext_vector_type(2)));

#define LOG2E 1.44269504088896f

// async global->LDS, 16B per lane. LDS dest = wave-uniform base + lane*16.
__device__ __forceinline__ void lds_load16(const void* g, void* l) {
  __builtin_amdgcn_global_load_lds((const __attribute__((address_space(1))) void*)g,
                                   (__attribute__((address_space(3))) void*)l, 16, 0, 0);
}

// pack 4 floats -> f16x4 via v_cvt_pkrtz_f16_f32
__device__ __forceinline__ f16x4 pack4_f16(float a, float b, float c, float d) {
  union { h16x2 h[2]; f16x4 f; } u;
  u.h[0] = __builtin_amdgcn_cvt_pkrtz(a, b);
  u.h[1] = __builtin_amdgcn_cvt_pkrtz(c, d);
  return u.f;
}

// 8B lane-pair exchange l <-> l^16 (quad 2j <-> 2j+1); conflict-free swizzle path
__device__ __forceinline__ f16x4 shflx16(f16x4 v) {
  union { f16x4 f; int i[2]; } u;
  u.f = v;
  u.i[0] = __shfl_xor(u.i[0], 16, 64);
  u.i[1] = __shfl_xor(u.i[1], 16, 64);
  return u.f;
}

#define MEMFENCE asm volatile("" ::: "memory")
#define WAITVM4  asm volatile("s_waitcnt vmcnt(4)" ::: "memory")
#define WAITVM0  asm volatile("s_waitcnt vmcnt(0)" ::: "memory")
// phase entry: barrier then drain LDS reads issued before it
#define PH_ENTER do { MEMFENCE; __builtin_amdgcn_s_barrier(); \
                      asm volatile("s_waitcnt lgkmcnt(0)" ::: "memory"); } while (0)
#define PH_EXIT  do { MEMFENCE; __builtin_amdgcn_s_barrier(); MEMFENCE; } while (0)

// ---------------------------------------------------------------------------
// Fused prelude: blocks 0..16383 cast q_in/v_in fp32->f16 (float4/thread);
// blocks 16384..17407 transpose-cast the 4 weight matrices (64x64 tiles).
// ---------------------------------------------------------------------------
__global__ __launch_bounds__(256) void prep(
    const float* __restrict__ q_in, const float* __restrict__ v_in,
    _Float16* __restrict__ q16, _Float16* __restrict__ v16,
    const float* __restrict__ W0, const float* __restrict__ W1,
    const float* __restrict__ W2, const float* __restrict__ W3,
    _Float16* __restrict__ T0, _Float16* __restrict__ T1,
    _Float16* __restrict__ T2, _Float16* __restrict__ T3) {
  __shared__ float L[64][65];
  const int bid = blockIdx.x;
  if (bid < 16384) {
    const float* in = (bid >> 13) ? v_in : q_in;
    _Float16* out = (bid >> 13) ? v16 : q16;
    int i = (bid & 8191) * 256 + threadIdx.x;   // n4 = 8192*256 exactly
    float4 v = ((const float4*)in)[i];
    f16x4 o = { (_Float16)v.x, (_Float16)v.y, (_Float16)v.z, (_Float16)v.w };
    ((f16x4*)out)[i] = o;
    return;
  }
  const int wb = bid - 16384;                   // 0..1023
  const float* W; _Float16* Wt;
  switch (wb >> 8) {
    case 0: W = W0; Wt = T0; break;
    case 1: W = W1; Wt = T1; break;
    case 2: W = W2; Wt = T2; break;
    default: W = W3; Wt = T3; break;
  }
  const int n0 = ((wb >> 4) & 15) * 64, k0 = (wb & 15) * 64;
  const int tx = threadIdx.x & 15, ty = threadIdx.x >> 4;
#pragma unroll
  for (int i = 0; i < 4; ++i) {
    float4 v = *(const float4*)&W[(size_t)(k0 + ty + 16 * i) * DMODEL + n0 + tx * 4];
    L[ty + 16 * i][tx * 4 + 0] = v.x;
    L[ty + 16 * i][tx * 4 + 1] = v.y;
    L[ty + 16 * i][tx * 4 + 2] = v.z;
    L[ty + 16 * i][tx * 4 + 3] = v.w;
  }
  __syncthreads();
#pragma unroll
  for (int i = 0; i < 4; ++i) {
    int n = n0 + ty + 16 * i;
    f16x4 o;
#pragma unroll
    for (int j = 0; j < 4; ++j) o[j] = (_Float16)L[tx * 4 + j][ty + 16 * i];
    *(f16x4*)&Wt[(size_t)n * DMODEL + k0 + tx * 4] = o;
  }
}

// ---------------------------------------------------------------------------
// QKV GEMM: 256x128-tile 2-phase counted-vmcnt schedule (halved r4 ledger).
// 512 threads = 8 waves (4M x 2N), wave tile 64x64 = acc[4][4], BK=64.
// LDS 96KB: 2 x (A 32KB + B 16KB), fragment-ordered 1KB groups (conflict-free
// ds_read_b128). Grid (8,32,3) = 768 blocks = 3 CLEAN rounds of 256 CUs
// (z-major dispatch: each z is one full round) — fixes the 1.5-round
// quantization of the 256² variant (384 blocks, half-GPU idle 2nd round).
// Per K-tile t (cur = t&1):
//   p0: rd A mi0-3 (8 b128) + B ni0-1 (4); stage B(t+1)->nxt (2 loads);
//       barrier+lgkm0; 16 MFMA (ni0-1); barrier.
//   p1: rd B ni2-3 (4); stage A(t+2)->cur (4 loads; A(t) reads retired at
//       p0's lgkm0 before its exit barrier); barrier+lgkm0; 16 MFMA (ni2-3);
//       vmcnt(4) [keep A(t+2); retire A(t+1)+B(t+1); never 0 till t=14];
//       barrier.
// Ledger: prologue A(0)4+B(0)2+A(1)4=10 -> vmcnt(4) retires A(0)+B(0);
// steady state enter-with-4, +2, +4, vmcnt(4); t=14 -> vmcnt(0); t=15 none.
// Per-XCD: 4 M-stripes (2MB A) + full B (2MB) = 4MB = L2.
// mode: 0 = f16 row-major (scaled), 2 = f16 [b,h,d,t] (V^T).
// ---------------------------------------------------------------------------
__device__ __forceinline__ void gemmqkv_body(
    const _Float16* __restrict__ A, const _Float16* __restrict__ Wt,
    const float* __restrict__ bias, void* __restrict__ Cout, float scale,
    int mode, _Float16* As0, _Float16* Bs0, _Float16* As1, _Float16* Bs1) {
  const int K = DMODEL;
  const int lane = threadIdx.x & 63, wave = threadIdx.x >> 6;
  const int m16 = lane & 15, quad = lane >> 4;
  const int wm = wave & 3;   // M quarter (64 rows)
  const int wn = wave >> 2;  // N half (64 cols)

  const int lin = blockIdx.x + blockIdx.y * gridDim.x;  // 0..255 within z
  const int xcd = lin & 7, idx = lin >> 3;              // idx 0..31
  const int m0 = (xcd * 4 + (idx & 3)) * 256;           // XCD-local M stripe
  const int n0 = (idx >> 2) * 128;

  // staging: A = 32 groups (m_t16 x kh), wave stages {wave*4..+3};
  //          B = 16 groups (n_t16 x kh), wave stages {wave*2, wave*2+1}.
  const _Float16* apg[4];
#pragma unroll
  for (int j = 0; j < 4; ++j)
    apg[j] = A + (size_t)(m0 + (wave * 2 + (j >> 1)) * 16 + m16) * K + (j & 1) * 32 + quad * 8;
  const _Float16* bpg[2];
#pragma unroll
  for (int j = 0; j < 2; ++j)
    bpg[j] = Wt + (size_t)(n0 + wave * 16 + m16) * K + j * 32 + quad * 8;

  auto stageA = [&](_Float16* Ab, int t) {
#pragma unroll
    for (int j = 0; j < 4; ++j)
      lds_load16(apg[j] + t * 64, Ab + (wave * 4 + j) * 512);
  };
  auto stageB = [&](_Float16* Bb, int t) {
#pragma unroll
    for (int j = 0; j < 2; ++j)
      lds_load16(bpg[j] + t * 64, Bb + (wave * 2 + j) * 512);
  };
  auto rdA = [&](const _Float16* Ab, int mi, int kh) {
    return *(const f16x8*)(Ab + (((wm * 4 + mi) * 2 + kh) * 64 + lane) * 8);
  };
  auto rdB = [&](const _Float16* Bb, int ni, int kh) {
    return *(const f16x8*)(Bb + (((wn * 4 + ni) * 2 + kh) * 64 + lane) * 8);
  };

  f32x4 acc[4][4] = {};

  auto tile_step = [&](int t, _Float16* Ac, const _Float16* Bc, _Float16* Bn) {
    f16x8 af[4][2], b01[2][2], b23[2][2];
    // ---- phase 0
#pragma unroll
    for (int mi = 0; mi < 4; ++mi) { af[mi][0] = rdA(Ac, mi, 0); af[mi][1] = rdA(Ac, mi, 1); }
#pragma unroll
    for (int ni = 0; ni < 2; ++ni) { b01[ni][0] = rdB(Bc, ni, 0); b01[ni][1] = rdB(Bc, ni, 1); }
    if (t < 15) stageB(Bn, t + 1);
    PH_ENTER;
    __builtin_amdgcn_s_setprio(1);
#pragma unroll
    for (int mi = 0; mi < 4; ++mi)
#pragma unroll
      for (int ni = 0; ni < 2; ++ni)
#pragma unroll
        for (int kh = 0; kh < 2; ++kh)
          acc[mi][ni] = __builtin_amdgcn_mfma_f32_16x16x32_f16(af[mi][kh], b01[ni][kh], acc[mi][ni], 0, 0, 0);
    __builtin_amdgcn_s_setprio(0);
    PH_EXIT;
    // ---- phase 1 (stage A(t+2) into cur A: region dead since p0's lgkm0)
#pragma unroll
    for (int ni = 0; ni < 2; ++ni) { b23[ni][0] = rdB(Bc, 2 + ni, 0); b23[ni][1] = rdB(Bc, 2 + ni, 1); }
    if (t < 14) stageA(Ac, t + 2);
    PH_ENTER;
    __builtin_amdgcn_s_setprio(1);
#pragma unroll
    for (int mi = 0; mi < 4; ++mi)
#pragma unroll
      for (int ni = 0; ni < 2; ++ni)
#pragma unroll
        for (int kh = 0; kh < 2; ++kh)
          acc[mi][2 + ni] = __builtin_amdgcn_mfma_f32_16x16x32_f16(af[mi][kh], b23[ni][kh], acc[mi][2 + ni], 0, 0, 0);
    __builtin_amdgcn_s_setprio(0);
    if (t < 14)       WAITVM4;   // keep A(t+2)'s 4 in flight
    else if (t == 14) WAITVM0;   // tail drain (A(15)+B(15))
    MEMFENCE; __builtin_amdgcn_s_barrier(); MEMFENCE;
  };

  // prologue: A(0) 4 + B(0) 2 + A(1) 4 = 10; vmcnt(4) keeps A(1)
  stageA(As0, 0); stageB(Bs0, 0); stageA(As1, 1);
  WAITVM4;
  MEMFENCE; __builtin_amdgcn_s_barrier(); MEMFENCE;

  for (int tp = 0; tp < 8; ++tp) {
    tile_step(2 * tp,     As0, Bs0, Bs1);
    tile_step(2 * tp + 1, As1, Bs1, Bs0);
  }

  // epilogue
  float bv[4];
#pragma unroll
  for (int ni = 0; ni < 4; ++ni) bv[ni] = bias[n0 + wn * 64 + ni * 16 + m16];

  if (mode == 2) {
    // V^T: reg r walks rows = t -> t-contiguous f16x4 per lane.
#pragma unroll
    for (int mi = 0; mi < 4; ++mi)
#pragma unroll
      for (int ni = 0; ni < 4; ++ni) {
        int row = m0 + (wm * 4 + mi) * 16 + quad * 4;
        int col = n0 + wn * 64 + ni * 16 + m16;
        int bb = row >> 11, tt = row & (T_SEQ - 1);
        int hh = col >> 6, dd = col & 63;
        f16x4 pv = pack4_f16(acc[mi][ni][0] + bv[ni], acc[mi][ni][1] + bv[ni],
                             acc[mi][ni][2] + bv[ni], acc[mi][ni][3] + bv[ni]);
        *(f16x4*)&((_Float16*)Cout)[(((size_t)bb * NH + hh) * HD + dd) * T_SEQ + tt] = pv;
      }
  } else {
#pragma unroll
    for (int mi = 0; mi < 4; ++mi)
#pragma unroll
      for (int r = 0; r < 4; ++r) {
        int row = m0 + (wm * 4 + mi) * 16 + quad * 4 + r;
#pragma unroll
        for (int ni = 0; ni < 4; ++ni) {
          int col = n0 + wn * 64 + ni * 16 + m16;
          float v = (acc[mi][ni][r] + bv[ni]) * scale;
          ((_Float16*)Cout)[(size_t)row * DMODEL + col] = (_Float16)v;
        }
      }
  }
}

// QKV projections fused; grid (8,32,3); z picks {Q,K,V}.
__global__ __launch_bounds__(512, 2) void gemm_qkv(
    const _Float16* __restrict__ Aq, const _Float16* __restrict__ Av,
    const _Float16* __restrict__ Wq, const _Float16* __restrict__ Wk,
    const _Float16* __restrict__ Wv,
    const float* __restrict__ bq, const float* __restrict__ bk,
    const float* __restrict__ bv,
    _Float16* __restrict__ Cq, _Float16* __restrict__ Ck, _Float16* __restrict__ Cv) {
  __shared__ _Float16 As[2][16384];  // 64KB
  __shared__ _Float16 Bs[2][8192];   // 32KB
  const _Float16* A; const _Float16* Wt; const float* bias; _Float16* C;
  float scale; int mode;
  if (blockIdx.z == 0)      { A = Aq; Wt = Wq; bias = bq; C = Cq; scale = 0.125f * LOG2E; mode = 0; }
  else if (blockIdx.z == 1) { A = Av; Wt = Wk; bias = bk; C = Ck; scale = 1.f; mode = 0; }
  else                      { A = Av; Wt = Wv; bias = bv; C = Cv; scale = 1.f; mode = 2; }
  gemmqkv_body(A, Wt, bias, C, scale, mode, As[0], Bs[0], As[1], Bs[1]);
}

// ---------------------------------------------------------------------------
// Output GEMM: m97-128² structure. 128x128 block, 4 waves, wave 64x64, BK=64,
// single-buffered 32KB LDS, 512 blocks at 3/CU.
// ---------------------------------------------------------------------------
__global__ __launch_bounds__(256, 3) void gemm_out(
    const _Float16* __restrict__ A, const _Float16* __restrict__ Wt,
    const float* __restrict__ bias, float* __restrict__ Cout) {
  __shared__ _Float16 As[128 * 64], Bs[128 * 64];
  const int K = DMODEL;
  const int lane = threadIdx.x & 63, wave = threadIdx.x >> 6;
  const int bid = blockIdx.x + blockIdx.y * gridDim.x;      // 0..511
  const int m0 = ((bid & 7) * 8 + ((bid >> 3) & 7)) * 128;  // XCD-local M stripe
  const int n0 = (bid >> 6) * 128;
  const int wr = (wave & 1) * 4, wc = (wave >> 1) * 4;
  const int m16 = lane & 15, quad = lane >> 4;

  const _Float16* ap[4]; const _Float16* bp[4];
#pragma unroll
  for (int j = 0; j < 4; ++j) {
    int g = wave * 4 + j;
    ap[j] = A  + (size_t)(m0 + (g >> 1) * 16 + m16) * K + (g & 1) * 32 + quad * 8;
    bp[j] = Wt + (size_t)(n0 + (g >> 1) * 16 + m16) * K + (g & 1) * 32 + quad * 8;
  }

  f32x4 acc[4][4] = {};

  for (int k0 = 0; k0 < 1024; k0 += 64) {
    __syncthreads();
#pragma unroll
    for (int j = 0; j < 4; ++j) {
      lds_load16(ap[j] + k0, As + (wave * 4 + j) * 512);
      lds_load16(bp[j] + k0, Bs + (wave * 4 + j) * 512);
    }
    __syncthreads();
#pragma unroll
    for (int s = 0; s < 2; ++s) {
      f16x8 bf[4];
#pragma unroll
      for (int ni = 0; ni < 4; ++ni)
        bf[ni] = *(const f16x8*)(Bs + (((wc + ni) * 2 + s) * 64 + lane) * 8);
#pragma unroll
      for (int mi = 0; mi < 4; ++mi) {
        f16x8 af = *(const f16x8*)(As + (((wr + mi) * 2 + s) * 64 + lane) * 8);
#pragma unroll
        for (int ni = 0; ni < 4; ++ni)
          acc[mi][ni] = __builtin_amdgcn_mfma_f32_16x16x32_f16(af, bf[ni], acc[mi][ni], 0, 0, 0);
      }
    }
  }

#pragma unroll
  for (int mi = 0; mi < 4; ++mi)
#pragma unroll
    for (int r = 0; r < 4; ++r) {
      int row = m0 + (wr + mi) * 16 + quad * 4 + r;
#pragma unroll
      for (int ni = 0; ni < 4; ++ni) {
        int col = n0 + (wc + ni) * 16 + m16;
        Cout[(size_t)row * DMODEL + col] = acc[mi][ni][r] + bias[col];
      }
    }
}

// ---------------------------------------------------------------------------
// Flash attention, f16 MFMA, 2-phase double-buffered K/V prefetch.
// QBLK=128: wave owns 32 Q-rows (mi<2); grid (16,16,4) = 1024 blocks =
// 4 blocks/CU = 4 waves/SIMD. P stays in registers via the l^16 partner
// exchange (conflict-free); V read at bit-reversed quad lane compensates the
// k-block permutation. Shift-free 2^s softmax. O aliases Q.
// ---------------------------------------------------------------------------
__global__ __launch_bounds__(256, 4) void attn_mfma(
    const _Float16* __restrict__ Q, const _Float16* __restrict__ Kb,
    const _Float16* __restrict__ Vt, _Float16* __restrict__ O) {
  __shared__ _Float16 Ks[2][64 * 64], Vs[2][64 * 64];  // 32KB total

  const int lane = threadIdx.x & 63, wave = threadIdx.x >> 6;
  const int m16 = lane & 15, quad = lane >> 4;
  const int pe = quad & 1;                            // partner-pair parity
  const int vlane = m16 | ((((quad & 1) << 1) | (quad >> 1)) << 4);  // bitrev quad
  const int h = blockIdx.x;                 // XCD = lin%8 -> h on XCD h%8
  const int q0 = blockIdx.y * 128;
  const int b = blockIdx.z;
  const int wq = wave * 32;

  f16x8 qf[2][2];
#pragma unroll
  for (int mi = 0; mi < 2; ++mi)
#pragma unroll
    for (int ki = 0; ki < 2; ++ki) {
      int q = q0 + wq + mi * 16 + m16;
      qf[mi][ki] = *(const f16x8*)(Q + (((size_t)b * T_SEQ + q) * NH + h) * HD + ki * 32 + quad * 8);
    }

  const _Float16 *kp[2], *vp[2];
#pragma unroll
  for (int i = 0; i < 2; ++i) {
    int g = wave * 128 + i * 64 + lane;     // chunk id 0..511
    int tk = (g >> 7) * 16 + (g & 15);
    int dkof = ((g >> 6) & 1) * 32 + ((g >> 4) & 3) * 8;
    kp[i] = Kb + (((size_t)b * T_SEQ + tk) * NH + h) * HD + dkof;
    int dvof = (g >> 7) * 16 + (g & 15);
    int tv = ((g >> 6) & 1) * 32 + ((g >> 4) & 3) * 8;
    vp[i] = Vt + (((size_t)b * NH + h) * HD + dvof) * T_SEQ + tv;
  }

  auto stageKV = [&](int c, int kv) {
#pragma unroll
    for (int i = 0; i < 2; ++i) {
      lds_load16(kp[i] + (size_t)kv * (NH * HD), Ks[c] + (wave * 2 + i) * 512);
      lds_load16(vp[i] + kv, Vs[c] + (wave * 2 + i) * 512);
    }
  };

  const f16x8 onef = {(_Float16)1, (_Float16)1, (_Float16)1, (_Float16)1,
                      (_Float16)1, (_Float16)1, (_Float16)1, (_Float16)1};

  f32x4 o_acc[2][4] = {};
  f32x4 l_acc[2] = {};

  // prologue: stage tile 0, drain
  stageKV(0, 0);
  WAITVM0;
  MEMFENCE; __builtin_amdgcn_s_barrier(); MEMFENCE;

  for (int t = 0; t < 32; ++t) {
    const int c = t & 1;
    if (t < 31) stageKV(c ^ 1, (t + 1) * 64);

    // S^T tiles: mfma(A=K, B=Q) -> row = t (quad*4+r), col = q (m16)
    f32x4 st[2][4] = {};
#pragma unroll
    for (int nt = 0; nt < 4; ++nt)
#pragma unroll
      for (int ki = 0; ki < 2; ++ki) {
        f16x8 kf = *(const f16x8*)(Ks[c] + ((nt * 2 + ki) * 64 + lane) * 8);
        __builtin_amdgcn_s_setprio(1);
#pragma unroll
        for (int mi = 0; mi < 2; ++mi)
          st[mi][nt] = __builtin_amdgcn_mfma_f32_16x16x32_f16(kf, qf[mi][ki], st[mi][nt], 0, 0, 0);
        __builtin_amdgcn_s_setprio(0);
      }

    // P = exp2(s) -> f16x4 per (mi,nt), kept in registers
    f16x4 pex[2][4];
#pragma unroll
    for (int mi = 0; mi < 2; ++mi)
#pragma unroll
      for (int nt = 0; nt < 4; ++nt)
        pex[mi][nt] = pack4_f16(__builtin_amdgcn_exp2f(st[mi][nt][0]),
                                __builtin_amdgcn_exp2f(st[mi][nt][1]),
                                __builtin_amdgcn_exp2f(st[mi][nt][2]),
                                __builtin_amdgcn_exp2f(st[mi][nt][3]));

    // O += P·V ; l += P·1  (P A-fragments assembled in-register via l^16 swap)
#pragma unroll
    for (int kt = 0; kt < 2; ++kt) {
      f16x8 pf[2];
#pragma unroll
      for (int mi = 0; mi < 2; ++mi) {
        f16x4 Aa = pex[mi][2 * kt], Bb = pex[mi][2 * kt + 1];
        f16x4 send = pe ? Aa : Bb;
        f16x4 recv = shflx16(send);
        union { f16x4 h[2]; f16x8 w; } u;
        u.h[0] = pe ? recv : Aa;
        u.h[1] = pe ? Bb : recv;
        pf[mi] = u.w;
        l_acc[mi] = __builtin_amdgcn_mfma_f32_16x16x32_f16(pf[mi], onef, l_acc[mi], 0, 0, 0);
      }
#pragma unroll
      for (int nd = 0; nd < 4; ++nd) {
        f16x8 vf = *(const f16x8*)(Vs[c] + ((nd * 2 + kt) * 64 + vlane) * 8);
        __builtin_amdgcn_s_setprio(1);
#pragma unroll
        for (int mi = 0; mi < 2; ++mi)
          o_acc[mi][nd] = __builtin_amdgcn_mfma_f32_16x16x32_f16(pf[mi], vf, o_acc[mi][nd], 0, 0, 0);
        __builtin_amdgcn_s_setprio(0);
      }
    }

    WAITVM0;  // next tile resident (issued a full compute-phase ago)
    MEMFENCE; __builtin_amdgcn_s_barrier(); MEMFENCE;
  }

#pragma unroll
  for (int mi = 0; mi < 2; ++mi)
#pragma unroll
    for (int r = 0; r < 4; ++r) {
      float inv = 1.f / l_acc[mi][r];
      int q = q0 + wq + mi * 16 + quad * 4 + r;
#pragma unroll
      for (int nd = 0; nd < 4; ++nd) {
        int d = nd * 16 + m16;
        O[(((size_t)b * T_SEQ + q) * NH + h) * HD + d] = (_Float16)(o_acc[mi][nd][r] * inv);
      }
    }
}

// ---------------------------------------------------------------------------
extern "C" void kernel_launch(void* const* d_in, const int* in_sizes, int n_in,
                              void* d_out, int out_size, void* d_ws, size_t ws_size,
                              hipStream_t stream) {
  const float* q_in = (const float*)d_in[0];
  const float* v_in = (const float*)d_in[1];
  const float* Wq   = (const float*)d_in[2];
  const float* bq   = (const float*)d_in[3];
  const float* Wk   = (const float*)d_in[4];
  const float* bk   = (const float*)d_in[5];
  const float* Wv   = (const float*)d_in[6];
  const float* bv   = (const float*)d_in[7];
  const float* Wo   = (const float*)d_in[8];
  const float* bo   = (const float*)d_in[9];
  float* out = (float*)d_out;

  const size_t MB = 1u << 20;
  char* ws = (char*)d_ws;
  _Float16* q16  = (_Float16*)(ws);            // A for Q projection
  _Float16* v16  = (_Float16*)(ws + 16 * MB);  // A for K/V projections
  _Float16* qbuf = (_Float16*)(ws + 32 * MB);  // Q out; attn O aliases this
  _Float16* kbuf = (_Float16*)(ws + 48 * MB);  // K out
  _Float16* vtb  = (_Float16*)(ws + 64 * MB);  // V^T out [b,h,d,t]
  _Float16* Wqt  = (_Float16*)(ws + 80 * MB);
  _Float16* Wkt  = (_Float16*)(ws + 82 * MB);
  _Float16* Wvt  = (_Float16*)(ws + 84 * MB);
  _Float16* Wot  = (_Float16*)(ws + 86 * MB);

  prep<<<dim3(16384 + 1024), 256, 0, stream>>>(q_in, v_in, q16, v16,
                                               Wq, Wk, Wv, Wo, Wqt, Wkt, Wvt, Wot);

  gemm_qkv<<<dim3(8, 32, 3), 512, 0, stream>>>(q16, v16, Wqt, Wkt, Wvt, bq, bk, bv,
                                               qbuf, kbuf, vtb);

  attn_mfma<<<dim3(16, 16, 4), 256, 0, stream>>>(qbuf, kbuf, vtb, qbuf);

  gemm_out<<<dim3(8, 64), 256, 0, stream>>>(qbuf, Wot, bo, out);
}

// Round 10
// 329.730 us; speedup vs baseline: 1.1225x; 1.1225x over previous
//
#include <hip/hip_runtime.h>

#define BATCH  4
#define T_SEQ  2048
#define NH     16
#define DMODEL 1024
#define HD     64

typedef float    f32x4 __attribute__((ext_vector_type(4)));
typedef _Float16 f16x8 __attribute__((ext_vector_type(8)));
typedef _Float16 f16x4 __attribute__((ext_vector_type(4)));
typedef __fp16   h16x2 __attribute__((ext_vector_type(2)));

#define LOG2E 1.44269504088896f

// async global->LDS, 16B per lane. LDS dest = wave-uniform base + lane*16.
__device__ __forceinline__ void lds_load16(const void* g, void* l) {
  __builtin_amdgcn_global_load_lds((const __attribute__((address_space(1))) void*)g,
                                   (__attribute__((address_space(3))) void*)l, 16, 0, 0);
}

// pack 4 floats -> f16x4 via v_cvt_pkrtz_f16_f32
__device__ __forceinline__ f16x4 pack4_f16(float a, float b, float c, float d) {
  union { h16x2 h[2]; f16x4 f; } u;
  u.h[0] = __builtin_amdgcn_cvt_pkrtz(a, b);
  u.h[1] = __builtin_amdgcn_cvt_pkrtz(c, d);
  return u.f;
}

// 8B lane-pair exchange l <-> l^16 (quad 2j <-> 2j+1); conflict-free swizzle path
__device__ __forceinline__ f16x4 shflx16(f16x4 v) {
  union { f16x4 f; int i[2]; } u;
  u.f = v;
  u.i[0] = __shfl_xor(u.i[0], 16, 64);
  u.i[1] = __shfl_xor(u.i[1], 16, 64);
  return u.f;
}

#define MEMFENCE asm volatile("" ::: "memory")
#define WAITVM4  asm volatile("s_waitcnt vmcnt(4)" ::: "memory")
#define WAITVM0  asm volatile("s_waitcnt vmcnt(0)" ::: "memory")
// phase entry: barrier then drain LDS reads issued before it
#define PH_ENTER do { MEMFENCE; __builtin_amdgcn_s_barrier(); \
                      asm volatile("s_waitcnt lgkmcnt(0)" ::: "memory"); } while (0)
#define PH_EXIT  do { MEMFENCE; __builtin_amdgcn_s_barrier(); MEMFENCE; } while (0)

// ---------------------------------------------------------------------------
// Fused prelude: blocks 0..16383 cast q_in/v_in fp32->f16 (float4/thread);
// blocks 16384..17407 transpose-cast the 4 weight matrices (64x64 tiles).
// ---------------------------------------------------------------------------
__global__ __launch_bounds__(256) void prep(
    const float* __restrict__ q_in, const float* __restrict__ v_in,
    _Float16* __restrict__ q16, _Float16* __restrict__ v16,
    const float* __restrict__ W0, const float* __restrict__ W1,
    const float* __restrict__ W2, const float* __restrict__ W3,
    _Float16* __restrict__ T0, _Float16* __restrict__ T1,
    _Float16* __restrict__ T2, _Float16* __restrict__ T3) {
  __shared__ float L[64][65];
  const int bid = blockIdx.x;
  if (bid < 16384) {
    const float* in = (bid >> 13) ? v_in : q_in;
    _Float16* out = (bid >> 13) ? v16 : q16;
    int i = (bid & 8191) * 256 + threadIdx.x;   // n4 = 8192*256 exactly
    float4 v = ((const float4*)in)[i];
    f16x4 o = { (_Float16)v.x, (_Float16)v.y, (_Float16)v.z, (_Float16)v.w };
    ((f16x4*)out)[i] = o;
    return;
  }
  const int wb = bid - 16384;                   // 0..1023
  const float* W; _Float16* Wt;
  switch (wb >> 8) {
    case 0: W = W0; Wt = T0; break;
    case 1: W = W1; Wt = T1; break;
    case 2: W = W2; Wt = T2; break;
    default: W = W3; Wt = T3; break;
  }
  const int n0 = ((wb >> 4) & 15) * 64, k0 = (wb & 15) * 64;
  const int tx = threadIdx.x & 15, ty = threadIdx.x >> 4;
#pragma unroll
  for (int i = 0; i < 4; ++i) {
    float4 v = *(const float4*)&W[(size_t)(k0 + ty + 16 * i) * DMODEL + n0 + tx * 4];
    L[ty + 16 * i][tx * 4 + 0] = v.x;
    L[ty + 16 * i][tx * 4 + 1] = v.y;
    L[ty + 16 * i][tx * 4 + 2] = v.z;
    L[ty + 16 * i][tx * 4 + 3] = v.w;
  }
  __syncthreads();
#pragma unroll
  for (int i = 0; i < 4; ++i) {
    int n = n0 + ty + 16 * i;
    f16x4 o;
#pragma unroll
    for (int j = 0; j < 4; ++j) o[j] = (_Float16)L[tx * 4 + j][ty + 16 * i];
    *(f16x4*)&Wt[(size_t)n * DMODEL + k0 + tx * 4] = o;
  }
}

// ---------------------------------------------------------------------------
// 256x256 8-phase counted-vmcnt GEMM (measured best of 5 structures: 91us).
// 512 threads = 8 waves (2M x 4N), wave tile 128x64 = acc[8][4], BK=64.
// LDS 128KB: 2 buffers x (A 32KB + B 32KB), fragment-ordered (1KB groups,
// conflict-free ds_read_b128). K-tile t lives in buffer t&1.
//   p0: read A mi0-3 + B ni0-1; stage B0(t+1)->nbuf; MFMA mi0-3 x ni0-1
//   p1: read B ni2-3;           stage B1(t+1)->nbuf; MFMA mi0-3 x ni2-3
//   p2: read A mi4-7;                                MFMA mi4-7 x ni0-1
//   p3: stage A0+A1(t+2)->buf (A(t) reads drained);  MFMA mi4-7 x ni2-3
//       vmcnt(4) keeps A(t+2)'s 4 loads in flight; never 0 until tail.
// NOTE r9 lesson: 256x128 halved tiles stage 1.5x bytes per output ->
// regressed to 113us despite cleaner grid rounds. Tile efficiency wins.
// ---------------------------------------------------------------------------
__device__ __forceinline__ void gemm256_body(
    const _Float16* __restrict__ A, const _Float16* __restrict__ Wt,
    const float* __restrict__ bias, void* __restrict__ Cout, float scale,
    int mode, _Float16* As0, _Float16* Bs0, _Float16* As1, _Float16* Bs1) {
  const int K = DMODEL;
  const int lane = threadIdx.x & 63, wave = threadIdx.x >> 6;
  const int m16 = lane & 15, quad = lane >> 4;
  const int wm = wave & 1;   // M half (128 rows)
  const int wn = wave >> 1;  // N quarter (64 cols)

  const int lin = blockIdx.x + blockIdx.y * gridDim.x;  // 0..127
  const int wg = (lin & 7) * 16 + (lin >> 3);           // XCD-contiguous
  const int m0 = (wg >> 2) * 256;
  const int n0 = (wg & 3) * 256;

  const int kof = (wave & 1) * 32 + quad * 8;
  const _Float16* aB[2][2]; const _Float16* bB[2][2];
#pragma unroll
  for (int h = 0; h < 2; ++h)
#pragma unroll
    for (int j = 0; j < 2; ++j) {
      int r = h * 128 + (wave >> 1) * 16 + 64 * j + m16;
      aB[h][j] = A  + (size_t)(m0 + r) * K + kof;
      bB[h][j] = Wt + (size_t)(n0 + r) * K + kof;
    }

  auto stageA = [&](_Float16* Ab, int h, int t) {
#pragma unroll
    for (int j = 0; j < 2; ++j)
      lds_load16(aB[h][j] + t * 64, Ab + (h * 16 + wave + 8 * j) * 512);
  };
  auto stageB = [&](_Float16* Bb, int h, int t) {
#pragma unroll
    for (int j = 0; j < 2; ++j)
      lds_load16(bB[h][j] + t * 64, Bb + (h * 16 + wave + 8 * j) * 512);
  };
  auto rdA = [&](const _Float16* Ab, int mi, int kh) {
    return *(const f16x8*)(Ab + (((wm * 8 + mi) * 2 + kh) * 64 + lane) * 8);
  };
  auto rdB = [&](const _Float16* Bb, int ni, int kh) {
    return *(const f16x8*)(Bb + (((wn * 4 + ni) * 2 + kh) * 64 + lane) * 8);
  };

  f32x4 acc[8][4] = {};

  auto tile_step = [&](int t, _Float16* Ac, const _Float16* Bc, _Float16* Bn) {
    f16x8 a03[4][2], a47[4][2], b01[2][2], b23[2][2];
    // ---- phase 0
#pragma unroll
    for (int mi = 0; mi < 4; ++mi) { a03[mi][0] = rdA(Ac, mi, 0); a03[mi][1] = rdA(Ac, mi, 1); }
#pragma unroll
    for (int ni = 0; ni < 2; ++ni) { b01[ni][0] = rdB(Bc, ni, 0); b01[ni][1] = rdB(Bc, ni, 1); }
    if (t < 15) stageB(Bn, 0, t + 1);
    PH_ENTER;
    __builtin_amdgcn_s_setprio(1);
#pragma unroll
    for (int mi = 0; mi < 4; ++mi)
#pragma unroll
      for (int ni = 0; ni < 2; ++ni)
#pragma unroll
        for (int kh = 0; kh < 2; ++kh)
          acc[mi][ni] = __builtin_amdgcn_mfma_f32_16x16x32_f16(a03[mi][kh], b01[ni][kh], acc[mi][ni], 0, 0, 0);
    __builtin_amdgcn_s_setprio(0);
    PH_EXIT;
    // ---- phase 1
#pragma unroll
    for (int ni = 0; ni < 2; ++ni) { b23[ni][0] = rdB(Bc, 2 + ni, 0); b23[ni][1] = rdB(Bc, 2 + ni, 1); }
    if (t < 15) stageB(Bn, 1, t + 1);
    PH_ENTER;
    __builtin_amdgcn_s_setprio(1);
#pragma unroll
    for (int mi = 0; mi < 4; ++mi)
#pragma unroll
      for (int ni = 0; ni < 2; ++ni)
#pragma unroll
        for (int kh = 0; kh < 2; ++kh)
          acc[mi][2 + ni] = __builtin_amdgcn_mfma_f32_16x16x32_f16(a03[mi][kh], b23[ni][kh], acc[mi][2 + ni], 0, 0, 0);
    __builtin_amdgcn_s_setprio(0);
    PH_EXIT;
    // ---- phase 2 (last A(t) LDS reads; drained at PH_ENTER's lgkmcnt(0))
#pragma unroll
    for (int mi = 0; mi < 4; ++mi) { a47[mi][0] = rdA(Ac, 4 + mi, 0); a47[mi][1] = rdA(Ac, 4 + mi, 1); }
    PH_ENTER;
    __builtin_amdgcn_s_setprio(1);
#pragma unroll
    for (int mi = 0; mi < 4; ++mi)
#pragma unroll
      for (int ni = 0; ni < 2; ++ni)
#pragma unroll
        for (int kh = 0; kh < 2; ++kh)
          acc[4 + mi][ni] = __builtin_amdgcn_mfma_f32_16x16x32_f16(a47[mi][kh], b01[ni][kh], acc[4 + mi][ni], 0, 0, 0);
    __builtin_amdgcn_s_setprio(0);
    PH_EXIT;
    // ---- phase 3 (A(t+2) -> current A buffer: region dead since p2 drain)
    if (t < 14) { stageA(Ac, 0, t + 2); stageA(Ac, 1, t + 2); }
    PH_ENTER;
    __builtin_amdgcn_s_setprio(1);
#pragma unroll
    for (int mi = 0; mi < 4; ++mi)
#pragma unroll
      for (int ni = 0; ni < 2; ++ni)
#pragma unroll
        for (int kh = 0; kh < 2; ++kh)
          acc[4 + mi][2 + ni] = __builtin_amdgcn_mfma_f32_16x16x32_f16(a47[mi][kh], b23[ni][kh], acc[4 + mi][2 + ni], 0, 0, 0);
    __builtin_amdgcn_s_setprio(0);
    if (t < 14)       WAITVM4;
    else if (t == 14) WAITVM0;
    MEMFENCE; __builtin_amdgcn_s_barrier(); MEMFENCE;
  };

  // prologue
  stageA(As0, 0, 0); stageA(As0, 1, 0);
  stageB(Bs0, 0, 0); stageB(Bs0, 1, 0);
  stageA(As1, 0, 1); stageA(As1, 1, 1);
  WAITVM4;
  MEMFENCE; __builtin_amdgcn_s_barrier(); MEMFENCE;

  for (int tp = 0; tp < 8; ++tp) {
    tile_step(2 * tp,     As0, Bs0, Bs1);
    tile_step(2 * tp + 1, As1, Bs1, Bs0);
  }

  // epilogue
  float bv[4];
#pragma unroll
  for (int ni = 0; ni < 4; ++ni) bv[ni] = bias[n0 + wn * 64 + ni * 16 + m16];

  if (mode == 2) {
#pragma unroll
    for (int mi = 0; mi < 8; ++mi)
#pragma unroll
      for (int ni = 0; ni < 4; ++ni) {
        int row = m0 + wm * 128 + mi * 16 + quad * 4;
        int col = n0 + wn * 64 + ni * 16 + m16;
        int bb = row >> 11, tt = row & (T_SEQ - 1);
        int hh = col >> 6, dd = col & 63;
        f16x4 pv = pack4_f16(acc[mi][ni][0] + bv[ni], acc[mi][ni][1] + bv[ni],
                             acc[mi][ni][2] + bv[ni], acc[mi][ni][3] + bv[ni]);
        *(f16x4*)&((_Float16*)Cout)[(((size_t)bb * NH + hh) * HD + dd) * T_SEQ + tt] = pv;
      }
  } else if (mode == 0) {
#pragma unroll
    for (int mi = 0; mi < 8; ++mi)
#pragma unroll
      for (int r = 0; r < 4; ++r) {
        int row = m0 + wm * 128 + mi * 16 + quad * 4 + r;
#pragma unroll
        for (int ni = 0; ni < 4; ++ni) {
          int col = n0 + wn * 64 + ni * 16 + m16;
          float v = (acc[mi][ni][r] + bv[ni]) * scale;
          ((_Float16*)Cout)[(size_t)row * DMODEL + col] = (_Float16)v;
        }
      }
  } else {
#pragma unroll
    for (int mi = 0; mi < 8; ++mi)
#pragma unroll
      for (int r = 0; r < 4; ++r) {
        int row = m0 + wm * 128 + mi * 16 + quad * 4 + r;
#pragma unroll
        for (int ni = 0; ni < 4; ++ni) {
          int col = n0 + wn * 64 + ni * 16 + m16;
          ((float*)Cout)[(size_t)row * DMODEL + col] = acc[mi][ni][r] + bv[ni];
        }
      }
  }
}

// QKV projections fused; grid (4,32,3); z picks {Q,K,V}.
__global__ __launch_bounds__(512, 2) void gemm_qkv(
    const _Float16* __restrict__ Aq, const _Float16* __restrict__ Av,
    const _Float16* __restrict__ Wq, const _Float16* __restrict__ Wk,
    const _Float16* __restrict__ Wv,
    const float* __restrict__ bq, const float* __restrict__ bk,
    const float* __restrict__ bv,
    _Float16* __restrict__ Cq, _Float16* __restrict__ Ck, _Float16* __restrict__ Cv) {
  __shared__ _Float16 As[2][16384], Bs[2][16384];  // 128KB
  const _Float16* A; const _Float16* Wt; const float* bias; _Float16* C;
  float scale; int mode;
  if (blockIdx.z == 0)      { A = Aq; Wt = Wq; bias = bq; C = Cq; scale = 0.125f * LOG2E; mode = 0; }
  else if (blockIdx.z == 1) { A = Av; Wt = Wk; bias = bk; C = Ck; scale = 1.f; mode = 0; }
  else                      { A = Av; Wt = Wv; bias = bv; C = Cv; scale = 1.f; mode = 2; }
  gemm256_body(A, Wt, bias, C, scale, mode, As[0], Bs[0], As[1], Bs[1]);
}

// ---------------------------------------------------------------------------
// Output GEMM: m97-128² structure. 128x128 block, 4 waves, wave 64x64, BK=64,
// single-buffered 32KB LDS, 512 blocks all co-resident at 3/CU.
// ---------------------------------------------------------------------------
__global__ __launch_bounds__(256, 3) void gemm_out(
    const _Float16* __restrict__ A, const _Float16* __restrict__ Wt,
    const float* __restrict__ bias, float* __restrict__ Cout) {
  __shared__ _Float16 As[128 * 64], Bs[128 * 64];
  const int K = DMODEL;
  const int lane = threadIdx.x & 63, wave = threadIdx.x >> 6;
  const int bid = blockIdx.x + blockIdx.y * gridDim.x;      // 0..511
  const int m0 = ((bid & 7) * 8 + ((bid >> 3) & 7)) * 128;  // XCD-local M stripe
  const int n0 = (bid >> 6) * 128;
  const int wr = (wave & 1) * 4, wc = (wave >> 1) * 4;
  const int m16 = lane & 15, quad = lane >> 4;

  const _Float16* ap[4]; const _Float16* bp[4];
#pragma unroll
  for (int j = 0; j < 4; ++j) {
    int g = wave * 4 + j;
    ap[j] = A  + (size_t)(m0 + (g >> 1) * 16 + m16) * K + (g & 1) * 32 + quad * 8;
    bp[j] = Wt + (size_t)(n0 + (g >> 1) * 16 + m16) * K + (g & 1) * 32 + quad * 8;
  }

  f32x4 acc[4][4] = {};

  for (int k0 = 0; k0 < 1024; k0 += 64) {
    __syncthreads();
#pragma unroll
    for (int j = 0; j < 4; ++j) {
      lds_load16(ap[j] + k0, As + (wave * 4 + j) * 512);
      lds_load16(bp[j] + k0, Bs + (wave * 4 + j) * 512);
    }
    __syncthreads();
#pragma unroll
    for (int s = 0; s < 2; ++s) {
      f16x8 bf[4];
#pragma unroll
      for (int ni = 0; ni < 4; ++ni)
        bf[ni] = *(const f16x8*)(Bs + (((wc + ni) * 2 + s) * 64 + lane) * 8);
#pragma unroll
      for (int mi = 0; mi < 4; ++mi) {
        f16x8 af = *(const f16x8*)(As + (((wr + mi) * 2 + s) * 64 + lane) * 8);
#pragma unroll
        for (int ni = 0; ni < 4; ++ni)
          acc[mi][ni] = __builtin_amdgcn_mfma_f32_16x16x32_f16(af, bf[ni], acc[mi][ni], 0, 0, 0);
      }
    }
  }

#pragma unroll
  for (int mi = 0; mi < 4; ++mi)
#pragma unroll
    for (int r = 0; r < 4; ++r) {
      int row = m0 + (wr + mi) * 16 + quad * 4 + r;
#pragma unroll
      for (int ni = 0; ni < 4; ++ni) {
        int col = n0 + (wc + ni) * 16 + m16;
        Cout[(size_t)row * DMODEL + col] = acc[mi][ni][r] + bias[col];
      }
    }
}

// ---------------------------------------------------------------------------
// Flash attention, f16 MFMA, 2-phase double-buffered K/V prefetch.
// QBLK=128: wave owns 32 Q-rows (mi<2); grid (16,16,4) = 1024 blocks =
// 4 blocks/CU = 4 waves/SIMD. P stays in registers via the l^16 partner
// exchange (conflict-free); V read at bit-reversed quad lane compensates the
// k-block permutation. setprio consolidated to 2 cluster-pairs per iter
// (was 16 micro-pairs = 32 SALU/iter on the chain). Shift-free 2^s softmax.
// ---------------------------------------------------------------------------
__global__ __launch_bounds__(256, 4) void attn_mfma(
    const _Float16* __restrict__ Q, const _Float16* __restrict__ Kb,
    const _Float16* __restrict__ Vt, _Float16* __restrict__ O) {
  __shared__ _Float16 Ks[2][64 * 64], Vs[2][64 * 64];  // 32KB total

  const int lane = threadIdx.x & 63, wave = threadIdx.x >> 6;
  const int m16 = lane & 15, quad = lane >> 4;
  const int pe = quad & 1;                            // partner-pair parity
  const int vlane = m16 | ((((quad & 1) << 1) | (quad >> 1)) << 4);  // bitrev quad
  const int h = blockIdx.x;                 // XCD = lin%8 -> h on XCD h%8
  const int q0 = blockIdx.y * 128;
  const int b = blockIdx.z;
  const int wq = wave * 32;

  f16x8 qf[2][2];
#pragma unroll
  for (int mi = 0; mi < 2; ++mi)
#pragma unroll
    for (int ki = 0; ki < 2; ++ki) {
      int q = q0 + wq + mi * 16 + m16;
      qf[mi][ki] = *(const f16x8*)(Q + (((size_t)b * T_SEQ + q) * NH + h) * HD + ki * 32 + quad * 8);
    }

  const _Float16 *kp[2], *vp[2];
#pragma unroll
  for (int i = 0; i < 2; ++i) {
    int g = wave * 128 + i * 64 + lane;     // chunk id 0..511
    int tk = (g >> 7) * 16 + (g & 15);
    int dkof = ((g >> 6) & 1) * 32 + ((g >> 4) & 3) * 8;
    kp[i] = Kb + (((size_t)b * T_SEQ + tk) * NH + h) * HD + dkof;
    int dvof = (g >> 7) * 16 + (g & 15);
    int tv = ((g >> 6) & 1) * 32 + ((g >> 4) & 3) * 8;
    vp[i] = Vt + (((size_t)b * NH + h) * HD + dvof) * T_SEQ + tv;
  }

  auto stageKV = [&](int c, int kv) {
#pragma unroll
    for (int i = 0; i < 2; ++i) {
      lds_load16(kp[i] + (size_t)kv * (NH * HD), Ks[c] + (wave * 2 + i) * 512);
      lds_load16(vp[i] + kv, Vs[c] + (wave * 2 + i) * 512);
    }
  };

  const f16x8 onef = {(_Float16)1, (_Float16)1, (_Float16)1, (_Float16)1,
                      (_Float16)1, (_Float16)1, (_Float16)1, (_Float16)1};

  f32x4 o_acc[2][4] = {};
  f32x4 l_acc[2] = {};

  // prologue: stage tile 0, drain
  stageKV(0, 0);
  WAITVM0;
  MEMFENCE; __builtin_amdgcn_s_barrier(); MEMFENCE;

  for (int t = 0; t < 32; ++t) {
    const int c = t & 1;
    if (t < 31) stageKV(c ^ 1, (t + 1) * 64);

    // S^T tiles: mfma(A=K, B=Q) -> row = t (quad*4+r), col = q (m16)
    f32x4 st[2][4] = {};
    __builtin_amdgcn_s_setprio(1);
#pragma unroll
    for (int nt = 0; nt < 4; ++nt)
#pragma unroll
      for (int ki = 0; ki < 2; ++ki) {
        f16x8 kf = *(const f16x8*)(Ks[c] + ((nt * 2 + ki) * 64 + lane) * 8);
#pragma unroll
        for (int mi = 0; mi < 2; ++mi)
          st[mi][nt] = __builtin_amdgcn_mfma_f32_16x16x32_f16(kf, qf[mi][ki], st[mi][nt], 0, 0, 0);
      }
    __builtin_amdgcn_s_setprio(0);

    // P = exp2(s) -> f16x4 per (mi,nt), kept in registers
    f16x4 pex[2][4];
#pragma unroll
    for (int mi = 0; mi < 2; ++mi)
#pragma unroll
      for (int nt = 0; nt < 4; ++nt)
        pex[mi][nt] = pack4_f16(__builtin_amdgcn_exp2f(st[mi][nt][0]),
                                __builtin_amdgcn_exp2f(st[mi][nt][1]),
                                __builtin_amdgcn_exp2f(st[mi][nt][2]),
                                __builtin_amdgcn_exp2f(st[mi][nt][3]));

    // O += P·V ; l += P·1  (P A-fragments assembled in-register via l^16 swap)
    __builtin_amdgcn_s_setprio(1);
#pragma unroll
    for (int kt = 0; kt < 2; ++kt) {
      f16x8 pf[2];
#pragma unroll
      for (int mi = 0; mi < 2; ++mi) {
        f16x4 Aa = pex[mi][2 * kt], Bb = pex[mi][2 * kt + 1];
        f16x4 send = pe ? Aa : Bb;
        f16x4 recv = shflx16(send);
        union { f16x4 h[2]; f16x8 w; } u;
        u.h[0] = pe ? recv : Aa;
        u.h[1] = pe ? Bb : recv;
        pf[mi] = u.w;
        l_acc[mi] = __builtin_amdgcn_mfma_f32_16x16x32_f16(pf[mi], onef, l_acc[mi], 0, 0, 0);
      }
#pragma unroll
      for (int nd = 0; nd < 4; ++nd) {
        f16x8 vf = *(const f16x8*)(Vs[c] + ((nd * 2 + kt) * 64 + vlane) * 8);
#pragma unroll
        for (int mi = 0; mi < 2; ++mi)
          o_acc[mi][nd] = __builtin_amdgcn_mfma_f32_16x16x32_f16(pf[mi], vf, o_acc[mi][nd], 0, 0, 0);
      }
    }
    __builtin_amdgcn_s_setprio(0);

    WAITVM0;  // next tile resident (issued a full compute-phase ago)
    MEMFENCE; __builtin_amdgcn_s_barrier(); MEMFENCE;
  }

#pragma unroll
  for (int mi = 0; mi < 2; ++mi)
#pragma unroll
    for (int r = 0; r < 4; ++r) {
      float inv = 1.f / l_acc[mi][r];
      int q = q0 + wq + mi * 16 + quad * 4 + r;
#pragma unroll
      for (int nd = 0; nd < 4; ++nd) {
        int d = nd * 16 + m16;
        O[(((size_t)b * T_SEQ + q) * NH + h) * HD + d] = (_Float16)(o_acc[mi][nd][r] * inv);
      }
    }
}

// ---------------------------------------------------------------------------
extern "C" void kernel_launch(void* const* d_in, const int* in_sizes, int n_in,
                              void* d_out, int out_size, void* d_ws, size_t ws_size,
                              hipStream_t stream) {
  const float* q_in = (const float*)d_in[0];
  const float* v_in = (const float*)d_in[1];
  const float* Wq   = (const float*)d_in[2];
  const float* bq   = (const float*)d_in[3];
  const float* Wk   = (const float*)d_in[4];
  const float* bk   = (const float*)d_in[5];
  const float* Wv   = (const float*)d_in[6];
  const float* bv   = (const float*)d_in[7];
  const float* Wo   = (const float*)d_in[8];
  const float* bo   = (const float*)d_in[9];
  float* out = (float*)d_out;

  const size_t MB = 1u << 20;
  char* ws = (char*)d_ws;
  _Float16* q16  = (_Float16*)(ws);            // A for Q projection
  _Float16* v16  = (_Float16*)(ws + 16 * MB);  // A for K/V projections
  _Float16* qbuf = (_Float16*)(ws + 32 * MB);  // Q out; attn O aliases this
  _Float16* kbuf = (_Float16*)(ws + 48 * MB);  // K out
  _Float16* vtb  = (_Float16*)(ws + 64 * MB);  // V^T out [b,h,d,t]
  _Float16* Wqt  = (_Float16*)(ws + 80 * MB);
  _Float16* Wkt  = (_Float16*)(ws + 82 * MB);
  _Float16* Wvt  = (_Float16*)(ws + 84 * MB);
  _Float16* Wot  = (_Float16*)(ws + 86 * MB);

  prep<<<dim3(16384 + 1024), 256, 0, stream>>>(q_in, v_in, q16, v16,
                                               Wq, Wk, Wv, Wo, Wqt, Wkt, Wvt, Wot);

  gemm_qkv<<<dim3(4, 32, 3), 512, 0, stream>>>(q16, v16, Wqt, Wkt, Wvt, bq, bk, bv,
                                               qbuf, kbuf, vtb);

  attn_mfma<<<dim3(16, 16, 4), 256, 0, stream>>>(qbuf, kbuf, vtb, qbuf);

  gemm_out<<<dim3(8, 64), 256, 0, stream>>>(qbuf, Wot, bo, out);
}